// Round 7
// baseline (553.945 us; speedup 1.0000x reference)
//
#include <hip/hip_runtime.h>
#include <cstdint>

typedef __attribute__((ext_vector_type(8))) short short8;
typedef __attribute__((ext_vector_type(4))) float f32x4;

constexpr int SEQ   = 2048;
constexpr int INSZ  = 256;   // K
constexpr int OUTSZ = 256;

__device__ __forceinline__ ushort f2bf(float f) {
  union { float f; uint32_t u; } v; v.f = f;
  uint32_t u = v.u;
  return (ushort)((u + 0x7FFFu + ((u >> 16) & 1u)) >> 16);  // RNE
}
__device__ __forceinline__ uint32_t pk2(float a, float b) {
  return (uint32_t)f2bf(a) | ((uint32_t)f2bf(b) << 16);
}

// ---------------------------------------------------------------------------
// Kernel 1: W_b = U[idx[b]] @ V, bf16, stored in MFMA B-fragment order:
//   ushort index = b*65536 + k5*8192 + nb*512 + lane*8 + j
// where k5 = k>>5, nb = o>>4, lane = (o&15) + ((k>>3)&3)*16, j = k&7.
// A wave's B fragment (16x32 subtile) is ONE coalesced 1KB load.
// ---------------------------------------------------------------------------
__global__ __launch_bounds__(256) void synth_w(
    const float* __restrict__ U, const float* __restrict__ V,
    const int* __restrict__ idx, ushort* __restrict__ wsW)
{
  const int b   = blockIdx.y;
  const int kb  = blockIdx.x;     // 0..3 -> local k window [kb*64, kb*64+64)
  const int tid = threadIdx.x;
  const int ch  = idx[b];
  const float u0 = U[ch*4+0], u1 = U[ch*4+1], u2 = U[ch*4+2], u3 = U[ch*4+3];

  __shared__ ushort tile[64][260];   // [k_local][o], padded to spread banks

  const int o4    = (tid & 63) * 4;
  const int kbase = (tid >> 6) * 16;
  for (int kk = 0; kk < 16; ++kk) {
    const int k  = kbase + kk;
    const int gk = kb*64 + k;
    const float* vp = V + (size_t)gk*OUTSZ + o4;
    float4 a = *(const float4*)(vp);
    float4 c = *(const float4*)(vp + 65536);
    float4 d = *(const float4*)(vp + 131072);
    float4 e = *(const float4*)(vp + 196608);
    ushort4 pkv;
    pkv.x = f2bf(u0*a.x + u1*c.x + u2*d.x + u3*e.x);
    pkv.y = f2bf(u0*a.y + u1*c.y + u2*d.y + u3*e.y);
    pkv.z = f2bf(u0*a.z + u1*c.z + u2*d.z + u3*e.z);
    pkv.w = f2bf(u0*a.w + u1*c.w + u2*d.w + u3*e.w);
    *(ushort4*)(&tile[k][o4]) = pkv;
  }
  __syncthreads();

  for (int s = 0; s < 8; ++s) {
    const int c      = s*256 + tid;
    const int kshalf = c >> 10;
    const int nb     = (c >> 6) & 15;
    const int lane   = c & 63;
    const int o      = nb*16 + (lane & 15);
    const int k0     = kshalf*32 + (lane >> 4)*8;
    uint4 pkv;
    pkv.x = (uint32_t)tile[k0+0][o] | ((uint32_t)tile[k0+1][o] << 16);
    pkv.y = (uint32_t)tile[k0+2][o] | ((uint32_t)tile[k0+3][o] << 16);
    pkv.z = (uint32_t)tile[k0+4][o] | ((uint32_t)tile[k0+5][o] << 16);
    pkv.w = (uint32_t)tile[k0+6][o] | ((uint32_t)tile[k0+7][o] << 16);
    uint4* dst = (uint4*)(wsW + (size_t)b*65536 + (size_t)(2*kb + kshalf)*8192
                              + nb*512 + lane*8);
    *dst = pkv;
  }
}

// ---------------------------------------------------------------------------
// Kernel 2 (persistent pipeline): each of 1024 blocks owns 512 rows of one
// batch = 16 half-tiles of 32 rows. Double-buffered 16KB A-LDS. Per tile:
// issue next tile's 8 global loads (held in 32 VGPR) -> k-loop(cur) ->
// convert+ds_write(next) -> 1 barrier -> stores drain under next k-loop.
// Continuous HBM read issue over the block's whole lifetime.
// ---------------------------------------------------------------------------
__global__ __launch_bounds__(256, 4) void lr_gemm(
    const float* __restrict__ x, const int* __restrict__ idx,
    const float* __restrict__ bias, const ushort* __restrict__ wsW,
    float* __restrict__ out)
{
  __shared__ ushort ldsA[2][32*256];   // 16KB each, XOR-swizzled rows

  // XCD swizzle: 1024 = 8*128 -> 32 batches per XCD (wsW slice = 4MB = L2)
  const int wg  = blockIdx.x;
  const int swz = (wg & 7) * 128 + (wg >> 3);
  const int b   = swz >> 2;        // 0..255
  const int q   = swz & 3;         // quarter: rows [q*512, q*512+512)

  const int tid  = threadIdx.x;
  const int lane = tid & 63;
  const int wave = tid >> 6;       // owns cols [wave*64, wave*64+64)
  const int hi16 = lane >> 4;
  const int lo16 = lane & 15;

  const float*  xb  = x + ((size_t)b*SEQ + q*512)*INSZ;
  const ushort* wbp = wsW + (size_t)b*65536 + wave*2048 + lane*8;

  const int srow = tid >> 5;       // 0..7 (stage row base, step 8)
  const int c8   = tid & 31;       // 8-float chunk in row
  const int wswz = (c8*16) ^ ((srow & 7) << 4);   // (its*8+srow)&7 == srow

  float4 s[4][2];
  // ---- prologue: stage tile 0
  {
    const float* base = xb;
    #pragma unroll
    for (int its = 0; its < 4; ++its) {
      const float* p = base + (size_t)(its*8 + srow)*INSZ + c8*8;
      s[its][0] = *(const float4*)p;
      s[its][1] = *(const float4*)(p + 4);
    }
    #pragma unroll
    for (int its = 0; its < 4; ++its) {
      uint4 pkv;
      pkv.x = pk2(s[its][0].x, s[its][0].y); pkv.y = pk2(s[its][0].z, s[its][0].w);
      pkv.z = pk2(s[its][1].x, s[its][1].y); pkv.w = pk2(s[its][1].z, s[its][1].w);
      *(uint4*)((char*)ldsA[0] + (its*8 + srow)*512 + wswz) = pkv;
    }
  }
  __syncthreads();

  const int ch = idx[b];
  float bv[4];
  #pragma unroll
  for (int n = 0; n < 4; ++n) bv[n] = bias[(size_t)ch*OUTSZ + wave*64 + n*16 + lo16];

  float* outb = out + ((size_t)b*SEQ + q*512)*OUTSZ;
  const int sx = (lo16 & 7) << 4;

  int cur = 0;
  for (int t = 0; t < 16; ++t) {
    // ---- issue next tile's loads FIRST (in flight during k-loop)
    if (t < 15) {
      const float* base = xb + (size_t)(t+1)*32*INSZ;
      #pragma unroll
      for (int its = 0; its < 4; ++its) {
        const float* p = base + (size_t)(its*8 + srow)*INSZ + c8*8;
        s[its][0] = *(const float4*)p;
        s[its][1] = *(const float4*)(p + 4);
      }
    }

    // ---- k-loop over buf[cur]
    f32x4 acc[2][4] = {};
    const char* aB = (const char*)ldsA[cur] + lo16*512;
    #pragma unroll
    for (int k5 = 0; k5 < 8; ++k5) {
      short8 bf[4], af[2];
      #pragma unroll
      for (int n = 0; n < 4; ++n)
        bf[n] = *(const short8*)(wbp + (size_t)k5*8192 + n*512);
      #pragma unroll
      for (int m = 0; m < 2; ++m)
        af[m] = *(const short8*)(aB + m*8192 + ((k5*64 + hi16*16) ^ sx));
      #pragma unroll
      for (int m = 0; m < 2; ++m)
        #pragma unroll
        for (int n = 0; n < 4; ++n)
          acc[m][n] = __builtin_amdgcn_mfma_f32_16x16x32_bf16(af[m], bf[n], acc[m][n], 0, 0, 0);
    }

    // ---- convert + ds_write next tile into the other buffer
    if (t < 15) {
      #pragma unroll
      for (int its = 0; its < 4; ++its) {
        uint4 pkv;
        pkv.x = pk2(s[its][0].x, s[its][0].y); pkv.y = pk2(s[its][0].z, s[its][0].w);
        pkv.z = pk2(s[its][1].x, s[its][1].y); pkv.w = pk2(s[its][1].z, s[its][1].w);
        *(uint4*)((char*)ldsA[cur ^ 1] + (its*8 + srow)*512 + wswz) = pkv;
      }
    }
    __syncthreads();   // buf[cur^1] visible; stores below drain under next k-loop

    // ---- stores for tile t (+bias), after barrier
    #pragma unroll
    for (int m = 0; m < 2; ++m) {
      const int r = t*32 + m*16 + hi16*4;
      #pragma unroll
      for (int n = 0; n < 4; ++n) {
        const int col = wave*64 + n*16 + lo16;
        #pragma unroll
        for (int j = 0; j < 4; ++j)
          outb[(size_t)(r + j)*OUTSZ + col] = acc[m][n][j] + bv[n];
      }
    }
    cur ^= 1;
  }
}

extern "C" void kernel_launch(void* const* d_in, const int* in_sizes, int n_in,
                              void* d_out, int out_size, void* d_ws, size_t ws_size,
                              hipStream_t stream) {
  const float* x    = (const float*)d_in[0];
  const int*   idx  = (const int*)d_in[1];
  const float* U    = (const float*)d_in[2];
  const float* V    = (const float*)d_in[3];
  const float* bias = (const float*)d_in[4];
  float* out  = (float*)d_out;
  ushort* wsW = (ushort*)d_ws;     // 256*65536*2 = 32 MiB

  synth_w<<<dim3(4, 256), 256, 0, stream>>>(U, V, idx, wsW);
  lr_gemm<<<1024, 256, 0, stream>>>(x, idx, bias, wsW, out);
}

// Round 8
// 398.003 us; speedup vs baseline: 1.3918x; 1.3918x over previous
//
#include <hip/hip_runtime.h>
#include <cstdint>

typedef __attribute__((ext_vector_type(8))) short short8;
typedef __attribute__((ext_vector_type(4))) float f32x4;

constexpr int SEQ   = 2048;
constexpr int INSZ  = 256;   // K
constexpr int OUTSZ = 256;

__device__ __forceinline__ ushort f2bf(float f) {
  union { float f; uint32_t u; } v; v.f = f;
  uint32_t u = v.u;
  return (ushort)((u + 0x7FFFu + ((u >> 16) & 1u)) >> 16);  // RNE
}
__device__ __forceinline__ uint32_t pk2(float a, float b) {
  return (uint32_t)f2bf(a) | ((uint32_t)f2bf(b) << 16);
}

// ---------------------------------------------------------------------------
// Kernel 1: W_b = U[idx[b]] @ V, bf16, stored in MFMA B-fragment order:
//   ushort index = b*65536 + k5*8192 + nb*512 + lane*8 + j
// where k5 = k>>5, nb = o>>4, lane = (o&15) + ((k>>3)&3)*16, j = k&7.
// A wave's B fragment (16x32 subtile) is ONE coalesced 1KB load.
// ---------------------------------------------------------------------------
__global__ __launch_bounds__(256) void synth_w(
    const float* __restrict__ U, const float* __restrict__ V,
    const int* __restrict__ idx, ushort* __restrict__ wsW)
{
  const int b   = blockIdx.y;
  const int kb  = blockIdx.x;     // 0..3 -> local k window [kb*64, kb*64+64)
  const int tid = threadIdx.x;
  const int ch  = idx[b];
  const float u0 = U[ch*4+0], u1 = U[ch*4+1], u2 = U[ch*4+2], u3 = U[ch*4+3];

  __shared__ ushort tile[64][260];   // [k_local][o], padded to spread banks

  const int o4    = (tid & 63) * 4;
  const int kbase = (tid >> 6) * 16;
  for (int kk = 0; kk < 16; ++kk) {
    const int k  = kbase + kk;
    const int gk = kb*64 + k;
    const float* vp = V + (size_t)gk*OUTSZ + o4;
    float4 a = *(const float4*)(vp);
    float4 c = *(const float4*)(vp + 65536);
    float4 d = *(const float4*)(vp + 131072);
    float4 e = *(const float4*)(vp + 196608);
    ushort4 pkv;
    pkv.x = f2bf(u0*a.x + u1*c.x + u2*d.x + u3*e.x);
    pkv.y = f2bf(u0*a.y + u1*c.y + u2*d.y + u3*e.y);
    pkv.z = f2bf(u0*a.z + u1*c.z + u2*d.z + u3*e.z);
    pkv.w = f2bf(u0*a.w + u1*c.w + u2*d.w + u3*e.w);
    *(ushort4*)(&tile[k][o4]) = pkv;
  }
  __syncthreads();

  for (int s = 0; s < 8; ++s) {
    const int c      = s*256 + tid;
    const int kshalf = c >> 10;
    const int nb     = (c >> 6) & 15;
    const int lane   = c & 63;
    const int o      = nb*16 + (lane & 15);
    const int k0     = kshalf*32 + (lane >> 4)*8;
    uint4 pkv;
    pkv.x = (uint32_t)tile[k0+0][o] | ((uint32_t)tile[k0+1][o] << 16);
    pkv.y = (uint32_t)tile[k0+2][o] | ((uint32_t)tile[k0+3][o] << 16);
    pkv.z = (uint32_t)tile[k0+4][o] | ((uint32_t)tile[k0+5][o] << 16);
    pkv.w = (uint32_t)tile[k0+6][o] | ((uint32_t)tile[k0+7][o] << 16);
    uint4* dst = (uint4*)(wsW + (size_t)b*65536 + (size_t)(2*kb + kshalf)*8192
                              + nb*512 + lane*8);
    *dst = pkv;
  }
}

// ---------------------------------------------------------------------------
// Kernel 2 (fine-grained one-shot blocks): 16384 blocks x 128 threads.
// Each block: ONE 32-row tile. stage(16KB LDS) -> barrier -> k-loop -> store.
// 8 blocks/CU resident, 64 dispatch generations: lifecycle phases interleave
// across blocks so the HBM read stream never idles. No reg-prefetch (compiler
// sinks it), no persistence (kills generational overlap).
// ---------------------------------------------------------------------------
__global__ __launch_bounds__(128, 4) void lr_gemm(
    const float* __restrict__ x, const int* __restrict__ idx,
    const float* __restrict__ bias, const ushort* __restrict__ wsW,
    float* __restrict__ out)
{
  __shared__ ushort ldsA[32*256];   // 16 KB, XOR-swizzled rows

  // XCD swizzle: 16384 = 8*2048 -> 32 consecutive batches per XCD,
  // blocks of one batch dispatched together on one XCD (W_b stays in L2).
  const int wg  = blockIdx.x;
  const int swz = (wg & 7) * 2048 + (wg >> 3);
  const int b   = swz >> 6;          // 0..255
  const int n0  = (swz & 63) * 32;   // row tile

  const int tid  = threadIdx.x;
  const int lane = tid & 63;
  const int wave = tid >> 6;         // 0..1, owns cols [wave*128, +128)
  const int hi16 = lane >> 4;
  const int lo16 = lane & 15;

  const float* xb = x + ((size_t)b*SEQ + n0)*INSZ;

  // ---- stage: 32 rows x 256 f32 -> bf16 swizzled LDS (8 iters/thread)
  #pragma unroll
  for (int it = 0; it < 8; ++it) {
    const int chunk = it*128 + tid;     // 0..1023 chunks of 8 floats
    const int row   = chunk >> 5;       // 0..31
    const int c8    = chunk & 31;
    const float* src = xb + (size_t)row*INSZ + c8*8;
    float4 f0 = *(const float4*)(src);
    float4 f1 = *(const float4*)(src + 4);
    uint4 pkv;
    pkv.x = pk2(f0.x, f0.y); pkv.y = pk2(f0.z, f0.w);
    pkv.z = pk2(f1.x, f1.y); pkv.w = pk2(f1.z, f1.w);
    *(uint4*)((char*)ldsA + row*512 + ((c8*16) ^ ((row & 7) << 4))) = pkv;
  }
  __syncthreads();

  // ---- k-loop: acc[2 m][8 n], B direct from fragment-order wsW (L2)
  const ushort* wbp = wsW + (size_t)b*65536 + wave*4096 + lane*8;
  const char*   aB  = (const char*)ldsA + lo16*512;
  const int sx = (lo16 & 7) << 4;

  f32x4 acc[2][8] = {};
  #pragma unroll
  for (int k5 = 0; k5 < 8; ++k5) {
    short8 af[2];
    #pragma unroll
    for (int m = 0; m < 2; ++m)
      af[m] = *(const short8*)(aB + m*8192 + ((k5*64 + hi16*16) ^ sx));
    #pragma unroll
    for (int n = 0; n < 8; ++n) {
      short8 bf = *(const short8*)(wbp + (size_t)k5*8192 + n*512);
      acc[0][n] = __builtin_amdgcn_mfma_f32_16x16x32_bf16(af[0], bf, acc[0][n], 0, 0, 0);
      acc[1][n] = __builtin_amdgcn_mfma_f32_16x16x32_bf16(af[1], bf, acc[1][n], 0, 0, 0);
    }
  }

  // ---- epilogue: + bias, direct stores
  const int ch = idx[b];
  float bv[8];
  #pragma unroll
  for (int n = 0; n < 8; ++n)
    bv[n] = bias[(size_t)ch*OUTSZ + wave*128 + n*16 + lo16];

  float* outb = out + ((size_t)b*SEQ + n0)*OUTSZ;
  #pragma unroll
  for (int m = 0; m < 2; ++m) {
    const int r = m*16 + hi16*4;
    #pragma unroll
    for (int n = 0; n < 8; ++n) {
      const int col = wave*128 + n*16 + lo16;
      #pragma unroll
      for (int j = 0; j < 4; ++j)
        outb[(size_t)(r + j)*OUTSZ + col] = acc[m][n][j] + bv[n];
    }
  }
}

extern "C" void kernel_launch(void* const* d_in, const int* in_sizes, int n_in,
                              void* d_out, int out_size, void* d_ws, size_t ws_size,
                              hipStream_t stream) {
  const float* x    = (const float*)d_in[0];
  const int*   idx  = (const int*)d_in[1];
  const float* U    = (const float*)d_in[2];
  const float* V    = (const float*)d_in[3];
  const float* bias = (const float*)d_in[4];
  float* out  = (float*)d_out;
  ushort* wsW = (ushort*)d_ws;     // 256*65536*2 = 32 MiB

  synth_w<<<dim3(4, 256), 256, 0, stream>>>(U, V, idx, wsW);
  lr_gemm<<<16384, 128, 0, stream>>>(x, idx, bias, wsW, out);
}

// Round 9
// 256.888 us; speedup vs baseline: 2.1564x; 1.5493x over previous
//
#include <hip/hip_runtime.h>
#include <cstdint>

typedef __attribute__((ext_vector_type(8))) short short8;
typedef __attribute__((ext_vector_type(4))) float f32x4;

constexpr int SEQ   = 2048;
constexpr int INSZ  = 256;   // K
constexpr int OUTSZ = 256;

__device__ __forceinline__ ushort f2bf(float f) {
  union { float f; uint32_t u; } v; v.f = f;
  uint32_t u = v.u;
  return (ushort)((u + 0x7FFFu + ((u >> 16) & 1u)) >> 16);  // RNE
}
__device__ __forceinline__ uint32_t pk2(float a, float b) {
  return (uint32_t)f2bf(a) | ((uint32_t)f2bf(b) << 16);
}

// ---------------------------------------------------------------------------
// Kernel 1: W_b = U[idx[b]] @ V, bf16, stored in MFMA B-fragment order:
//   ushort index = b*65536 + k5*8192 + nb*512 + lane*8 + j
// where k5 = k>>5, nb = o>>4, lane = (o&15) + ((k>>3)&3)*16, j = k&7.
// A wave's B fragment (16x32 subtile) is ONE coalesced 1KB load.
// ---------------------------------------------------------------------------
__global__ __launch_bounds__(256) void synth_w(
    const float* __restrict__ U, const float* __restrict__ V,
    const int* __restrict__ idx, ushort* __restrict__ wsW)
{
  const int b   = blockIdx.y;
  const int kb  = blockIdx.x;     // 0..3 -> local k window [kb*64, kb*64+64)
  const int tid = threadIdx.x;
  const int ch  = idx[b];
  const float u0 = U[ch*4+0], u1 = U[ch*4+1], u2 = U[ch*4+2], u3 = U[ch*4+3];

  __shared__ ushort tile[64][260];   // [k_local][o], padded to spread banks

  const int o4    = (tid & 63) * 4;
  const int kbase = (tid >> 6) * 16;
  for (int kk = 0; kk < 16; ++kk) {
    const int k  = kbase + kk;
    const int gk = kb*64 + k;
    const float* vp = V + (size_t)gk*OUTSZ + o4;
    float4 a = *(const float4*)(vp);
    float4 c = *(const float4*)(vp + 65536);
    float4 d = *(const float4*)(vp + 131072);
    float4 e = *(const float4*)(vp + 196608);
    ushort4 pkv;
    pkv.x = f2bf(u0*a.x + u1*c.x + u2*d.x + u3*e.x);
    pkv.y = f2bf(u0*a.y + u1*c.y + u2*d.y + u3*e.y);
    pkv.z = f2bf(u0*a.z + u1*c.z + u2*d.z + u3*e.z);
    pkv.w = f2bf(u0*a.w + u1*c.w + u2*d.w + u3*e.w);
    *(ushort4*)(&tile[k][o4]) = pkv;
  }
  __syncthreads();

  for (int s = 0; s < 8; ++s) {
    const int c      = s*256 + tid;
    const int kshalf = c >> 10;
    const int nb     = (c >> 6) & 15;
    const int lane   = c & 63;
    const int o      = nb*16 + (lane & 15);
    const int k0     = kshalf*32 + (lane >> 4)*8;
    uint4 pkv;
    pkv.x = (uint32_t)tile[k0+0][o] | ((uint32_t)tile[k0+1][o] << 16);
    pkv.y = (uint32_t)tile[k0+2][o] | ((uint32_t)tile[k0+3][o] << 16);
    pkv.z = (uint32_t)tile[k0+4][o] | ((uint32_t)tile[k0+5][o] << 16);
    pkv.w = (uint32_t)tile[k0+6][o] | ((uint32_t)tile[k0+7][o] << 16);
    uint4* dst = (uint4*)(wsW + (size_t)b*65536 + (size_t)(2*kb + kshalf)*8192
                              + nb*512 + lane*8);
    *dst = pkv;
  }
}

// ---------------------------------------------------------------------------
// Kernel 2 (R5 skeleton, occupancy push): stage 64x256 A once (exactly 32768B
// LDS -> 5 blocks/CU by LDS), one barrier, 8 barrier-free K-slices with
// depth-2 B pipeline, direct scattered stores (no LDS bounce; R8 counters
// prove zero WRITE amplification).
// ---------------------------------------------------------------------------
__global__ __launch_bounds__(256, 4) void lr_gemm(
    const float* __restrict__ x, const int* __restrict__ idx,
    const float* __restrict__ bias, const ushort* __restrict__ wsW,
    float* __restrict__ out)
{
  __shared__ ushort ldsA[64*256];   // 32768 B exactly

  // XCD-aware swizzle (8192 = 8*1024): a batch's 32 blocks stay on one XCD
  const int wg  = blockIdx.x;
  const int swz = (wg & 7) * 1024 + (wg >> 3);
  const int b   = swz >> 5;
  const int n0  = (swz & 31) * 64;

  const int tid  = threadIdx.x;
  const int lane = tid & 63;
  const int wave = tid >> 6;      // owns cols [wave*64, wave*64+64)
  const int hi16 = lane >> 4;
  const int lo16 = lane & 15;

  const float*  xb  = x + ((size_t)b*SEQ + n0)*INSZ;
  const ushort* wbp = wsW + (size_t)b*65536 + wave*2048 + lane*8;

  // ---- pipeline prologue: issue B[k5=0] before A-stage (independent of LDS)
  short8 bcur[4], bnxt[4];
  #pragma unroll
  for (int n = 0; n < 4; ++n)
    bcur[n] = *(const short8*)(wbp + n*512);

  // ---- stage A: full 64x256 f32 tile -> bf16 swizzled LDS (once)
  #pragma unroll
  for (int it = 0; it < 8; ++it) {
    const int row = it*8 + (tid >> 5);
    const int c8  = tid & 31;
    const float* src = xb + (size_t)row*INSZ + c8*8;
    float4 f0 = *(const float4*)(src);
    float4 f1 = *(const float4*)(src + 4);
    uint4 pkv;
    pkv.x = pk2(f0.x, f0.y); pkv.y = pk2(f0.z, f0.w);
    pkv.z = pk2(f1.x, f1.y); pkv.w = pk2(f1.z, f1.w);
    *(uint4*)((char*)ldsA + row*512 + ((c8*16) ^ ((row & 7) << 4))) = pkv;
  }
  __syncthreads();   // the only barrier

  f32x4 acc[4][4] = {};
  const int sx = (lo16 & 7) << 4;
  const char* aB = (const char*)ldsA + lo16*512;

  #pragma unroll
  for (int k5 = 0; k5 < 8; ++k5) {
    if (k5 < 7) {
      #pragma unroll
      for (int n = 0; n < 4; ++n)
        bnxt[n] = *(const short8*)(wbp + (size_t)(k5+1)*8192 + n*512);
    }
    short8 af[4];
    #pragma unroll
    for (int m = 0; m < 4; ++m)
      af[m] = *(const short8*)(aB + m*8192 + ((k5*64 + hi16*16) ^ sx));
    #pragma unroll
    for (int m = 0; m < 4; ++m)
      #pragma unroll
      for (int n = 0; n < 4; ++n)
        acc[m][n] = __builtin_amdgcn_mfma_f32_16x16x32_bf16(af[m], bcur[n], acc[m][n], 0, 0, 0);
    #pragma unroll
    for (int n = 0; n < 4; ++n) bcur[n] = bnxt[n];
  }

  // ---- epilogue: + bias, direct stores
  const int ch = idx[b];
  const float* bb = bias + (size_t)ch*OUTSZ;
  float bv[4];
  #pragma unroll
  for (int n = 0; n < 4; ++n) bv[n] = bb[wave*64 + n*16 + lo16];

  float* outb = out + ((size_t)b*SEQ + n0)*OUTSZ;
  #pragma unroll
  for (int m = 0; m < 4; ++m) {
    const int rbase = m*16 + hi16*4;
    #pragma unroll
    for (int n = 0; n < 4; ++n) {
      const int col = wave*64 + n*16 + lo16;
      #pragma unroll
      for (int j = 0; j < 4; ++j)
        outb[(size_t)(rbase + j)*OUTSZ + col] = acc[m][n][j] + bv[n];
    }
  }
}

extern "C" void kernel_launch(void* const* d_in, const int* in_sizes, int n_in,
                              void* d_out, int out_size, void* d_ws, size_t ws_size,
                              hipStream_t stream) {
  const float* x    = (const float*)d_in[0];
  const int*   idx  = (const int*)d_in[1];
  const float* U    = (const float*)d_in[2];
  const float* V    = (const float*)d_in[3];
  const float* bias = (const float*)d_in[4];
  float* out  = (float*)d_out;
  ushort* wsW = (ushort*)d_ws;     // 256*65536*2 = 32 MiB

  synth_w<<<dim3(4, 256), 256, 0, stream>>>(U, V, idx, wsW);
  lr_gemm<<<8192, 256, 0, stream>>>(x, idx, bias, wsW, out);
}

// Round 10
// 255.741 us; speedup vs baseline: 2.1660x; 1.0045x over previous
//
#include <hip/hip_runtime.h>
#include <cstdint>

#define AS1 __attribute__((address_space(1)))
#define AS3 __attribute__((address_space(3)))

typedef __attribute__((ext_vector_type(8))) short short8;
typedef __attribute__((ext_vector_type(4))) float f32x4;

constexpr int SEQ   = 2048;
constexpr int INSZ  = 256;   // K
constexpr int OUTSZ = 256;

__device__ __forceinline__ ushort f2bf(float f) {
  union { float f; uint32_t u; } v; v.f = f;
  uint32_t u = v.u;
  return (ushort)((u + 0x7FFFu + ((u >> 16) & 1u)) >> 16);  // RNE
}
__device__ __forceinline__ uint32_t pk2(float a, float b) {
  return (uint32_t)f2bf(a) | ((uint32_t)f2bf(b) << 16);
}
__device__ __forceinline__ uint32_t cvtpk(float lo, float hi) {
  uint32_t r;
  asm("v_cvt_pk_bf16_f32 %0, %1, %2" : "=v"(r) : "v"(lo), "v"(hi));
  return r;
}

// ---------------------------------------------------------------------------
// Kernel 1: W_b = U[idx[b]] @ V, bf16, stored in MFMA B-fragment order:
//   ushort index = b*65536 + k5*8192 + nb*512 + lane*8 + j
// ---------------------------------------------------------------------------
__global__ __launch_bounds__(256) void synth_w(
    const float* __restrict__ U, const float* __restrict__ V,
    const int* __restrict__ idx, ushort* __restrict__ wsW)
{
  const int b   = blockIdx.y;
  const int kb  = blockIdx.x;     // 0..3 -> local k window [kb*64, kb*64+64)
  const int tid = threadIdx.x;
  const int ch  = idx[b];
  const float u0 = U[ch*4+0], u1 = U[ch*4+1], u2 = U[ch*4+2], u3 = U[ch*4+3];

  __shared__ ushort tile[64][260];

  const int o4    = (tid & 63) * 4;
  const int kbase = (tid >> 6) * 16;
  for (int kk = 0; kk < 16; ++kk) {
    const int k  = kbase + kk;
    const int gk = kb*64 + k;
    const float* vp = V + (size_t)gk*OUTSZ + o4;
    float4 a = *(const float4*)(vp);
    float4 c = *(const float4*)(vp + 65536);
    float4 d = *(const float4*)(vp + 131072);
    float4 e = *(const float4*)(vp + 196608);
    ushort4 pkv;
    pkv.x = f2bf(u0*a.x + u1*c.x + u2*d.x + u3*e.x);
    pkv.y = f2bf(u0*a.y + u1*c.y + u2*d.y + u3*e.y);
    pkv.z = f2bf(u0*a.z + u1*c.z + u2*d.z + u3*e.z);
    pkv.w = f2bf(u0*a.w + u1*c.w + u2*d.w + u3*e.w);
    *(ushort4*)(&tile[k][o4]) = pkv;
  }
  __syncthreads();

  for (int s = 0; s < 8; ++s) {
    const int c      = s*256 + tid;
    const int kshalf = c >> 10;
    const int nb     = (c >> 6) & 15;
    const int lane   = c & 63;
    const int o      = nb*16 + (lane & 15);
    const int k0     = kshalf*32 + (lane >> 4)*8;
    uint4 pkv;
    pkv.x = (uint32_t)tile[k0+0][o] | ((uint32_t)tile[k0+1][o] << 16);
    pkv.y = (uint32_t)tile[k0+2][o] | ((uint32_t)tile[k0+3][o] << 16);
    pkv.z = (uint32_t)tile[k0+4][o] | ((uint32_t)tile[k0+5][o] << 16);
    pkv.w = (uint32_t)tile[k0+6][o] | ((uint32_t)tile[k0+7][o] << 16);
    uint4* dst = (uint4*)(wsW + (size_t)b*65536 + (size_t)(2*kb + kshalf)*8192
                              + nb*512 + lane*8);
    *dst = pkv;
  }
}

// ---------------------------------------------------------------------------
// Kernel 2: gload_lds pipelined. A staged as f32 slabs [64 rows][32 k] via
// global_load_lds (zero-register, unsinkable) into a 4-slab LDS ring (32KB).
// Depth-3 prefetch, counted vmcnt + raw s_barrier per slab (no vmcnt(0)
// drain). f32->bf16 on the fragment path (v_cvt_pk_bf16_f32). Operand-swapped
// MFMA gives float4 stores.
// ---------------------------------------------------------------------------
__global__ __launch_bounds__(256, 4) void lr_gemm(
    const float* __restrict__ x, const int* __restrict__ idx,
    const float* __restrict__ bias, const ushort* __restrict__ wsW,
    float* __restrict__ out)
{
  __shared__ float ldsF[4][64*32];   // 4 slabs x 8 KB = 32768 B

  // XCD-aware swizzle (8192 = 8*1024)
  const int wg  = blockIdx.x;
  const int swz = (wg & 7) * 1024 + (wg >> 3);
  const int b   = swz >> 5;
  const int n0  = (swz & 31) * 64;

  const int tid  = threadIdx.x;
  const int lane = tid & 63;
  const int wave = tid >> 6;      // owns cols [wave*64, wave*64+64)
  const int hi16 = lane >> 4;
  const int lo16 = lane & 15;

  const float*  xb  = x + ((size_t)b*SEQ + n0)*INSZ;
  const ushort* wbp = wsW + (size_t)b*65536 + wave*2048 + lane*8;

  // stage slab S: 16 gload_lds (4/wave... 2/wave) of 1024B; src pre-swizzled
  // so LDS slot (row, c) holds x chunk (row, c ^ (row&7)); dest linear.
  const int csrc = (lane & 7) ^ (lane >> 3);   // (row&7) == lane>>3 per group
#define STAGE(S) do {                                                        \
    _Pragma("unroll")                                                        \
    for (int t = 0; t < 2; ++t) {                                            \
      const int g = wave*2 + t;              /* 8-row group 0..7 */          \
      const int r = g*8 + (lane >> 3);                                       \
      const float* srcp = xb + (size_t)r*INSZ + (S)*32 + csrc*4;             \
      float* dstp = &ldsF[(S) & 3][g*256];                                   \
      __builtin_amdgcn_global_load_lds((const AS1 void*)srcp,                \
                                       (AS3 void*)dstp, 16, 0, 0);           \
    } } while (0)

  STAGE(0); STAGE(1); STAGE(2);
  asm volatile("s_waitcnt vmcnt(4)" ::: "memory");   // slab0 landed
  __builtin_amdgcn_s_barrier();
  __builtin_amdgcn_sched_barrier(0);

  f32x4 acc[4][4] = {};
  const int s0idx = (hi16*2) ^ (lo16 & 7);   // slot of chunk hi16*2
  const int s1idx = s0idx ^ 1;

#define KSTEP(S, WSTR) do {                                                  \
    short8 bf[4], af[4];                                                     \
    _Pragma("unroll")                                                        \
    for (int n = 0; n < 4; ++n)                                              \
      bf[n] = *(const short8*)(wbp + (size_t)(S)*8192 + n*512);              \
    if ((S) < 5) STAGE((S)+3);                                               \
    const float* fb = &ldsF[(S) & 3][0];                                     \
    _Pragma("unroll")                                                        \
    for (int m = 0; m < 4; ++m) {                                            \
      const float* p = fb + (m*16 + lo16)*32;                                \
      float4 fa = *(const float4*)(p + s0idx*4);                             \
      float4 fc = *(const float4*)(p + s1idx*4);                             \
      union { uint32_t u[4]; short8 s8; } pk;                                \
      pk.u[0] = cvtpk(fa.x, fa.y); pk.u[1] = cvtpk(fa.z, fa.w);              \
      pk.u[2] = cvtpk(fc.x, fc.y); pk.u[3] = cvtpk(fc.z, fc.w);              \
      af[m] = pk.s8;                                                         \
    }                                                                        \
    _Pragma("unroll")                                                        \
    for (int m = 0; m < 4; ++m)                                              \
      _Pragma("unroll")                                                      \
      for (int n = 0; n < 4; ++n)                                            \
        acc[m][n] = __builtin_amdgcn_mfma_f32_16x16x32_bf16(                 \
            bf[n], af[m], acc[m][n], 0, 0, 0);                               \
    if ((S) < 7) {                                                           \
      __builtin_amdgcn_sched_barrier(0);                                     \
      asm volatile("s_waitcnt vmcnt(" WSTR ")" ::: "memory");                \
      __builtin_amdgcn_s_barrier();                                          \
      __builtin_amdgcn_sched_barrier(0);                                     \
    } } while (0)

  KSTEP(0, "4"); KSTEP(1, "4"); KSTEP(2, "4"); KSTEP(3, "4");
  KSTEP(4, "4"); KSTEP(5, "2"); KSTEP(6, "0"); KSTEP(7, "0");

  // ---- epilogue: swapped layout -> lane holds 4 consecutive out cols
  const int ch = idx[b];
  float* outb = out + ((size_t)b*SEQ + n0)*OUTSZ;
  #pragma unroll
  for (int n = 0; n < 4; ++n) {
    const float4 bv4 = *(const float4*)(bias + (size_t)ch*OUTSZ
                                        + wave*64 + n*16 + hi16*4);
    #pragma unroll
    for (int m = 0; m < 4; ++m) {
      float4 v;
      v.x = acc[m][n][0] + bv4.x;
      v.y = acc[m][n][1] + bv4.y;
      v.z = acc[m][n][2] + bv4.z;
      v.w = acc[m][n][3] + bv4.w;
      *(float4*)(outb + (size_t)(m*16 + lo16)*OUTSZ
                 + wave*64 + n*16 + hi16*4) = v;
    }
  }
#undef KSTEP
#undef STAGE
}

extern "C" void kernel_launch(void* const* d_in, const int* in_sizes, int n_in,
                              void* d_out, int out_size, void* d_ws, size_t ws_size,
                              hipStream_t stream) {
  const float* x    = (const float*)d_in[0];
  const int*   idx  = (const int*)d_in[1];
  const float* U    = (const float*)d_in[2];
  const float* V    = (const float*)d_in[3];
  const float* bias = (const float*)d_in[4];
  float* out  = (float*)d_out;
  ushort* wsW = (ushort*)d_ws;     // 256*65536*2 = 32 MiB

  synth_w<<<dim3(4, 256), 256, 0, stream>>>(U, V, idx, wsW);
  lr_gemm<<<8192, 256, 0, stream>>>(x, idx, bias, wsW, out);
}